// Round 5
// baseline (105.437 us; speedup 1.0000x reference)
//
#include <hip/hip_runtime.h>
#include <math.h>

#define NROWS 8192
#define DDIM  128
#define K20   28.853900817779268f        // 20 * log2(e)
#define K2    (K20 * K20)                // 832.5476
#define DTHR  8.3255f                    // 0.01 * K2 : self-pair mask (real pairs >> this)
#define NBLK  2080                       // sum_{I=0}^{63} (64-I) Jc-pair blocks

typedef _Float16 f16x8 __attribute__((ext_vector_type(8)));
typedef _Float16 f16x4 __attribute__((ext_vector_type(4)));
typedef float    f32x4 __attribute__((ext_vector_type(4)));

// Fragment-major layout for mfma_f32_16x16x32_f16 (16-row groups):
//   xf[g*2048 + kk*512 + l*8 + j] = x[i = g*16 + (l&15)][k = kk*32 + (l>>4)*8 + j]
//
// Triangular Jc-pair decomposition: block t -> (I, p), F(I) = I*(129-I)/2,
// p = t - F(I) in [0, 64-I). Block covers rows [I*128,+128) x cols
// [(2I+2p)*64, +128).  p==0 is the diagonal square (both pair orders computed,
// positives split out); p>=1 blocks are strictly above it and mirror col sums.
//
// ws layout (after xf), all float2 = (L, S):
//   rowP[64][8192] : slot p   -> row sums of block (I(row), p)
//   colP[64][8192] : slot I   -> mirrored col sums of block (I, p(col))
//   posP[8192]     : positive-pair sums (exp(-40d), exp(+20d)) from diag blocks
// Single writer per slot; finalize reads exactly the written slots:
//   row i (I=i>>7): n = sum_{p<64-I} rowP[p][i] + sum_{b<I} colP[b][i]  (64 loads)

// ---- fp32 -> f16 frag-major transform + zero out ----
__global__ void convert_kernel(const float* __restrict__ x,
                               _Float16* __restrict__ xf,
                               float* __restrict__ out) {
    int idx = (blockIdx.x * 256 + threadIdx.x) * 4;    // flat (i,k) element index
    float4 v = *(const float4*)(x + idx);
    f16x4 h = { (_Float16)v.x, (_Float16)v.y, (_Float16)v.z, (_Float16)v.w };
    const int i = idx >> 7, k = idx & 127;             // k multiple of 4
    const int lane = (((k >> 3) & 3) << 4) | (i & 15);
    const int dst = (i >> 4) * 2048 + (k >> 5) * 512 + lane * 8 + (k & 7);
    *(f16x4*)(xf + dst) = h;
    if (blockIdx.x == 0 && threadIdx.x == 0) out[0] = 0.0f;
}

// ---- unified pair kernel: 2080 blocks of 128x128, 4 waves of 32 rows ----
__global__ __launch_bounds__(256, 4) void pair_kernel(
        const _Float16* __restrict__ xf,
        float2* __restrict__ rowP,
        float2* __restrict__ colP,
        float2* __restrict__ posP) {
    __shared__ float shcL[4][128], shcS[4][128];

    // decode t -> (I, p): F(I) = I*(129-I)/2 (always even product)
    const int t = blockIdx.x;
    int I = (int)((129.0f - sqrtf(16641.0f - 8.0f * (float)t)) * 0.5f);
    I = I < 0 ? 0 : (I > 63 ? 63 : I);
    while (I * (129 - I) / 2 > t) --I;
    while ((I + 1) * (128 - I) / 2 <= t) ++I;
    const int p = t - I * (129 - I) / 2;
    const int Jc0 = 2 * I + 2 * p;               // first 64-col group of the pair

    const int w = threadIdx.x >> 6;
    const int lane = threadIdx.x & 63;
    const int i0 = I * 128 + w * 32;

    // A fragments resident: 2 strips x 4 k-chunks, one 1 KB coalesced load each
    const _Float16* ab = xf + (size_t)(I * 8 + w * 2) * 2048 + lane * 8;
    f16x8 a0[4], a1[4];
    #pragma unroll
    for (int kk = 0; kk < 4; ++kk) {
        a0[kk] = *(const f16x8*)(ab + kk * 512);
        a1[kk] = *(const f16x8*)(ab + 2048 + kk * 512);
    }

    float nL[8], nS[8];
    #pragma unroll
    for (int r = 0; r < 8; ++r) { nL[r] = 0.f; nS[r] = 0.f; }

    const _Float16* bb = xf + (size_t)(Jc0 * 4) * 2048 + lane * 8;  // tile g: +g*2048

    if (p != 0) {
        // ---------- mirrored off-diagonal block ----------
        f16x8 b0[4], b1[4];
        #pragma unroll
        for (int kk = 0; kk < 4; ++kk) b0[kk] = *(const f16x8*)(bb + kk * 512);

        auto compute = [&](f16x8 (&b)[4], int g) {
            f32x4 acc0 = {0.f,0.f,0.f,0.f}, acc1 = {0.f,0.f,0.f,0.f};
            #pragma unroll
            for (int kk = 0; kk < 4; ++kk) {
                acc0 = __builtin_amdgcn_mfma_f32_16x16x32_f16(a0[kk], b[kk], acc0, 0, 0, 0);
                acc1 = __builtin_amdgcn_mfma_f32_16x16x32_f16(a1[kk], b[kk], acc1, 0, 0, 0);
            }
            float cs = 0.f, cl = 0.f;
            #pragma unroll
            for (int r = 0; r < 4; ++r) {
                float d2s = fmaf(-2.0f * K2, acc0[r], 2.0f * K2);   // (20*log2e)^2 d^2
                float ds  = __builtin_amdgcn_sqrtf(d2s);
                float tt  = __builtin_amdgcn_exp2f(-ds);            // exp(-20 d)
                tt = (d2s < DTHR) ? 0.0f : tt;
                nS[r] += tt; cs += tt;
                nL[r] = fmaf(tt, tt, nL[r]); cl = fmaf(tt, tt, cl);
            }
            #pragma unroll
            for (int r = 0; r < 4; ++r) {
                float d2s = fmaf(-2.0f * K2, acc1[r], 2.0f * K2);
                float ds  = __builtin_amdgcn_sqrtf(d2s);
                float tt  = __builtin_amdgcn_exp2f(-ds);
                tt = (d2s < DTHR) ? 0.0f : tt;
                nS[4 + r] += tt; cs += tt;
                nL[4 + r] = fmaf(tt, tt, nL[4 + r]); cl = fmaf(tt, tt, cl);
            }
            // col sums over the wave's 32 rows (row groups live at lane bits 4,5)
            cs += __shfl_xor(cs, 16, 64);  cl += __shfl_xor(cl, 16, 64);
            cs += __shfl_xor(cs, 32, 64);  cl += __shfl_xor(cl, 32, 64);
            if (lane < 16) { shcS[w][g * 16 + lane] = cs; shcL[w][g * 16 + lane] = cl; }
        };

        // 8 col-tiles, 1-ahead register double buffer
        #pragma unroll
        for (int kk = 0; kk < 4; ++kk) b1[kk] = *(const f16x8*)(bb + 1 * 2048 + kk * 512);
        compute(b0, 0);
        #pragma unroll
        for (int kk = 0; kk < 4; ++kk) b0[kk] = *(const f16x8*)(bb + 2 * 2048 + kk * 512);
        compute(b1, 1);
        #pragma unroll
        for (int kk = 0; kk < 4; ++kk) b1[kk] = *(const f16x8*)(bb + 3 * 2048 + kk * 512);
        compute(b0, 2);
        #pragma unroll
        for (int kk = 0; kk < 4; ++kk) b0[kk] = *(const f16x8*)(bb + 4 * 2048 + kk * 512);
        compute(b1, 3);
        #pragma unroll
        for (int kk = 0; kk < 4; ++kk) b1[kk] = *(const f16x8*)(bb + 5 * 2048 + kk * 512);
        compute(b0, 4);
        #pragma unroll
        for (int kk = 0; kk < 4; ++kk) b0[kk] = *(const f16x8*)(bb + 6 * 2048 + kk * 512);
        compute(b1, 5);
        #pragma unroll
        for (int kk = 0; kk < 4; ++kk) b1[kk] = *(const f16x8*)(bb + 7 * 2048 + kk * 512);
        compute(b0, 6);
        compute(b1, 7);

        // row sums -> unique slot rowP[p][row]
        #pragma unroll
        for (int s = 0; s < 2; ++s) {
            #pragma unroll
            for (int r = 0; r < 4; ++r) {
                float aa = nL[s * 4 + r], ss = nS[s * 4 + r];
                #pragma unroll
                for (int m = 1; m < 16; m <<= 1) {
                    aa += __shfl_xor(aa, m, 64);
                    ss += __shfl_xor(ss, m, 64);
                }
                if ((lane & 15) == 0) {
                    const int row = i0 + s * 16 + (lane >> 4) * 4 + r;  // C/D row map
                    rowP[(size_t)p * NROWS + row] = make_float2(aa, ss);
                }
            }
        }

        // combine 4 waves' col sums -> unique slot colP[I][col]
        __syncthreads();
        if (threadIdx.x < 128) {
            const int c = threadIdx.x;
            colP[(size_t)I * NROWS + Jc0 * 64 + c] =
                make_float2(shcL[0][c] + shcL[1][c] + shcL[2][c] + shcL[3][c],
                            shcS[0][c] + shcS[1][c] + shcS[2][c] + shcS[3][c]);
        }
    } else {
        // ---------- diagonal square (p == 0): both orders, pos/neg split ----------
        const int rq = (lane >> 4) * 4;          // C/D row-quarter offset
        float qL[8], qS[8];
        #pragma unroll
        for (int r = 0; r < 8; ++r) { qL[r] = 0.f; qS[r] = 0.f; }

        f16x8 b[4];
        for (int g = 0; g < 8; ++g) {
            const _Float16* bp = bb + (size_t)g * 2048;
            #pragma unroll
            for (int kk = 0; kk < 4; ++kk) b[kk] = *(const f16x8*)(bp + kk * 512);

            f32x4 acc0 = {0.f,0.f,0.f,0.f}, acc1 = {0.f,0.f,0.f,0.f};
            #pragma unroll
            for (int kk = 0; kk < 4; ++kk) {
                acc0 = __builtin_amdgcn_mfma_f32_16x16x32_f16(a0[kk], b[kk], acc0, 0, 0, 0);
                acc1 = __builtin_amdgcn_mfma_f32_16x16x32_f16(a1[kk], b[kk], acc1, 0, 0, 0);
            }
            const int col8 = (I * 128 + g * 16 + (lane & 15)) >> 3;
            #pragma unroll
            for (int s = 0; s < 2; ++s) {
                const bool same = ((i0 + s * 16 + rq) >> 3) == col8;  // classes 8-aligned
                #pragma unroll
                for (int r = 0; r < 4; ++r) {
                    float acc = s ? acc1[r] : acc0[r];
                    float d2s = fmaf(-2.0f * K2, acc, 2.0f * K2);
                    float ds  = __builtin_amdgcn_sqrtf(d2s);
                    bool  ok  = !(d2s < DTHR);                        // self-pair mask
                    float tt  = ok ? __builtin_amdgcn_exp2f(-ds) : 0.f;  // exp(-20 d)
                    float pe  = ok ? __builtin_amdgcn_exp2f(ds)  : 0.f;  // exp(+20 d)
                    float tn  = same ? 0.f : tt;
                    float tp  = same ? tt  : 0.f;
                    float pp  = same ? pe  : 0.f;
                    nS[s * 4 + r] += tn; nL[s * 4 + r] = fmaf(tn, tn, nL[s * 4 + r]);
                    qS[s * 4 + r] += pp; qL[s * 4 + r] = fmaf(tp, tp, qL[s * 4 + r]);
                }
            }
        }

        // neg -> rowP[0][row], pos -> posP[row]
        #pragma unroll
        for (int s = 0; s < 2; ++s) {
            #pragma unroll
            for (int r = 0; r < 4; ++r) {
                float a = nL[s * 4 + r], bsum = nS[s * 4 + r];
                float c = qL[s * 4 + r], d = qS[s * 4 + r];
                #pragma unroll
                for (int m = 1; m < 16; m <<= 1) {
                    a += __shfl_xor(a, m, 64);  bsum += __shfl_xor(bsum, m, 64);
                    c += __shfl_xor(c, m, 64);  d += __shfl_xor(d, m, 64);
                }
                if ((lane & 15) == 0) {
                    const int row = i0 + s * 16 + (lane >> 4) * 4 + r;
                    rowP[row] = make_float2(a, bsum);
                    posP[row] = make_float2(c, d);
                }
            }
        }
    }
}

// ---- finalize: 1 thread per row, exactly 64 coalesced float2 loads each ----
__global__ void finalize_kernel(const float2* __restrict__ rowP,
                                const float2* __restrict__ colP,
                                const float2* __restrict__ posP,
                                float* __restrict__ out) {
    const int i = blockIdx.x * 128 + threadIdx.x;
    const int I = i >> 7;                         // uniform per wave (128 | i-range)

    float nl = 0.f, ns = 0.f;
    for (int p = 0; p < 64 - I; ++p) {
        float2 v = rowP[(size_t)p * NROWS + i];
        nl += v.x; ns += v.y;
    }
    for (int b = 0; b < I; ++b) {
        float2 v = colP[(size_t)b * NROWS + i];
        nl += v.x; ns += v.y;
    }
    float2 q = posP[i];

    float aLr  = 1.0f - q.x / (q.x + nl);
    float posL = logf(q.y) - 16.0f;               // log(sum exp(20(d-0.8)))
    float negL = logf(ns) + 22.0f;                // log(sum exp(20(1.1-d)))
    float v = aLr * (posL + negL);

    #pragma unroll
    for (int m = 1; m < 64; m <<= 1) v += __shfl_xor(v, m, 64);
    __shared__ float part[2];
    if ((threadIdx.x & 63) == 0) part[threadIdx.x >> 6] = v;
    __syncthreads();
    if (threadIdx.x == 0)
        atomicAdd(out, (part[0] + part[1]) * (1.0f / NROWS));
}

extern "C" void kernel_launch(void* const* d_in, const int* in_sizes, int n_in,
                              void* d_out, int out_size, void* d_ws, size_t ws_size,
                              hipStream_t stream) {
    const float* x = (const float*)d_in[0];
    float* out = (float*)d_out;

    _Float16* xf = (_Float16*)d_ws;                  // 2 MB, fragment-major
    float2* rowP = (float2*)(xf + NROWS * DDIM);     // [64][8192] 4 MB
    float2* colP = rowP + 64 * NROWS;                // [64][8192] 4 MB
    float2* posP = colP + 64 * NROWS;                // 64 KB  (~10 MB total << ws)

    convert_kernel<<<NROWS * DDIM / (256 * 4), 256, 0, stream>>>(x, xf, out);
    pair_kernel<<<NBLK, 256, 0, stream>>>(xf, rowP, colP, posP);
    finalize_kernel<<<NROWS / 128, 128, 0, stream>>>(rowP, colP, posP, out);
}

// Round 6
// 97.390 us; speedup vs baseline: 1.0826x; 1.0826x over previous
//
#include <hip/hip_runtime.h>
#include <math.h>

#define NROWS 8192
#define DDIM  128
#define K20   28.853900817779268f        // 20 * log2(e)
#define K2    (K20 * K20)                // 832.5476
#define DTHR  8.3255f                    // 0.01 * K2 : self-pair mask (real pairs >> this)

typedef _Float16 f16x8 __attribute__((ext_vector_type(8)));
typedef _Float16 f16x4 __attribute__((ext_vector_type(4)));
typedef _Float16 f16x2 __attribute__((ext_vector_type(2)));
typedef float    f32x4 __attribute__((ext_vector_type(4)));

#ifndef __has_builtin
#define __has_builtin(x) 0
#endif
#if __has_builtin(__builtin_amdgcn_fdot2)
#define HAVE_FDOT2 1
#else
#define HAVE_FDOT2 0
#endif

// Fragment-major layout for mfma_f32_16x16x32_f16 (16-row groups):
//   xf[g*2048 + kk*512 + l*8 + j] = x[i = g*16 + (l&15)][k = kk*32 + (l>>4)*8 + j]
// -> a wave's A/B fragment load for one k-chunk is one contiguous 1 KB dwordx4.
// ws layout (floats after xf): sums[0..N) = nL (sum exp(-40d)), [N..2N) = nS (sum exp(-20d))

// ---- fp32 -> f16 frag-major transform + zero sums/out ----
__global__ void convert_kernel(const float* __restrict__ x,
                               _Float16* __restrict__ xf,
                               float* __restrict__ sums,
                               float* __restrict__ out) {
    int idx = (blockIdx.x * 256 + threadIdx.x) * 4;    // flat (i,k) element index
    float4 v = *(const float4*)(x + idx);
    f16x4 h = { (_Float16)v.x, (_Float16)v.y, (_Float16)v.z, (_Float16)v.w };
    const int i = idx >> 7, k = idx & 127;             // k multiple of 4
    const int lane = (((k >> 3) & 3) << 4) | (i & 15);
    const int dst = (i >> 4) * 2048 + (k >> 5) * 512 + lane * 8 + (k & 7);
    *(f16x4*)(xf + dst) = h;
    if (threadIdx.x < 16) sums[blockIdx.x * 16 + threadIdx.x] = 0.0f;  // 1024*16 = 2*NROWS
    if (blockIdx.x == 0 && threadIdx.x == 0) out[0] = 0.0f;
}

// ---- main pair kernel: full matrix (all pairs as negatives; self excluded by
//      value; same-class pairs subtracted in finalize). Wave = 32-row strip
//      (two 16-row A fragments) x 256-col segment walked as 16 col-tiles of 16.
//      Grid 64x32 = 2048 blocks = 8192 waves (~8/SIMD slots, 6 resident via
//      launch_bounds) -- vs round 0's single 4-wave generation at 28% occupancy.
//      B tiles register-double-buffered so next-tile loads issue under the
//      current tile's MFMA + transcendental epilogue. ----
__global__ __launch_bounds__(256, 6) void pair_kernel(
        const _Float16* __restrict__ xf,
        float* __restrict__ sums) {
    const int w = threadIdx.x >> 6;
    const int lane = threadIdx.x & 63;
    const int ig = blockIdx.x * 4 + w;            // 32-row strip, 0..255
    const int i0 = ig * 32;
    const int ct0 = blockIdx.y * 16;              // first 16-col tile of segment

    // A fragments resident: 2 strips x 4 k-chunks, one 1 KB coalesced load each
    const _Float16* ab = xf + (size_t)(ig * 2) * 2048 + lane * 8;
    f16x8 a0[4], a1[4];
    #pragma unroll
    for (int kk = 0; kk < 4; ++kk) {
        a0[kk] = *(const f16x8*)(ab + kk * 512);
        a1[kk] = *(const f16x8*)(ab + 2048 + kk * 512);
    }

    float nL[8], nS[8];
    #pragma unroll
    for (int r = 0; r < 8; ++r) { nL[r] = 0.f; nS[r] = 0.f; }

    const _Float16* bb = xf + (size_t)ct0 * 2048 + lane * 8;

    f16x8 b0[4], b1[4];
    #pragma unroll
    for (int kk = 0; kk < 4; ++kk) b0[kk] = *(const f16x8*)(bb + kk * 512);

    auto compute = [&](f16x8 (&b)[4]) {
        f32x4 acc0 = {0.f,0.f,0.f,0.f}, acc1 = {0.f,0.f,0.f,0.f};
        #pragma unroll
        for (int kk = 0; kk < 4; ++kk) {
            acc0 = __builtin_amdgcn_mfma_f32_16x16x32_f16(a0[kk], b[kk], acc0, 0, 0, 0);
            acc1 = __builtin_amdgcn_mfma_f32_16x16x32_f16(a1[kk], b[kk], acc1, 0, 0, 0);
        }
        #pragma unroll
        for (int r = 0; r < 4; ++r) {
            float d2s = fmaf(-2.0f * K2, acc0[r], 2.0f * K2);    // (20*log2e)^2 * d^2
            float ds  = __builtin_amdgcn_sqrtf(d2s);             // NaN on self, masked below
            float tt  = __builtin_amdgcn_exp2f(-ds);             // exp(-20 d)
            tt = (d2s < DTHR) ? 0.0f : tt;                       // exact self-pair exclusion
            nS[r] += tt;
            nL[r] = fmaf(tt, tt, nL[r]);                         // exp(-40 d)
        }
        #pragma unroll
        for (int r = 0; r < 4; ++r) {
            float d2s = fmaf(-2.0f * K2, acc1[r], 2.0f * K2);
            float ds  = __builtin_amdgcn_sqrtf(d2s);
            float tt  = __builtin_amdgcn_exp2f(-ds);
            tt = (d2s < DTHR) ? 0.0f : tt;
            nS[4 + r] += tt;
            nL[4 + r] = fmaf(tt, tt, nL[4 + r]);
        }
    };

    // 16 col-tiles, 1-ahead register double buffer (wrap reload on last: harmless)
    for (int g = 0; g < 16; g += 2) {
        const _Float16* p1 = bb + (size_t)(g + 1) * 2048;
        #pragma unroll
        for (int kk = 0; kk < 4; ++kk) b1[kk] = *(const f16x8*)(p1 + kk * 512);
        compute(b0);
        const _Float16* p2 = bb + (size_t)((g + 2) & 15) * 2048;
        #pragma unroll
        for (int kk = 0; kk < 4; ++kk) b0[kk] = *(const f16x8*)(p2 + kk * 512);
        compute(b1);
    }

    // reduce across the 16 column-lanes per quarter; C/D map: col=lane&15,
    // row = s*16 + (lane>>4)*4 + r  (m89/m91)
    #pragma unroll
    for (int s = 0; s < 2; ++s) {
        #pragma unroll
        for (int r = 0; r < 4; ++r) {
            float aa = nL[s * 4 + r], ss = nS[s * 4 + r];
            #pragma unroll
            for (int m = 1; m < 16; m <<= 1) {
                aa += __shfl_xor(aa, m, 64);
                ss += __shfl_xor(ss, m, 64);
            }
            if ((lane & 15) == 0) {
                const int row = i0 + s * 16 + (lane >> 4) * 4 + r;
                atomicAdd(&sums[row], aa);
                atomicAdd(&sums[NROWS + row], ss);
            }
        }
    }
}

// ---- finalize + positive-pair correction, 8 threads per row (1024 waves).
//      Thread j of row i computes the single partner jj=j (skipped when j==ii),
//      then a 3-step shuffle combine; lane j==0 finishes the per-row loss. ----
__global__ void finalize_kernel(const _Float16* __restrict__ xf,
                                const float* __restrict__ sums,
                                float* __restrict__ out) {
    const int tid = threadIdx.x;
    const int i = blockIdx.x * 32 + (tid >> 3);   // row
    const int j = tid & 7;                        // partner slot
    const int g = i >> 4, ri = i & 15, ii = i & 7;
    const _Float16* base = xf + (size_t)g * 2048;

    float pL = 0.f, pS = 0.f, subL = 0.f, subS = 0.f;
    if (j != ii) {
        const int rj = ri - ii + j;               // same 16-row group (classes 8-aligned)
        float dot = 0.f;
        #pragma unroll
        for (int kk = 0; kk < 4; ++kk) {
            #pragma unroll
            for (int h = 0; h < 4; ++h) {
                f16x8 av = *(const f16x8*)(base + kk * 512 + ((h << 4) | ri) * 8);
                f16x8 bv = *(const f16x8*)(base + kk * 512 + ((h << 4) | rj) * 8);
#if HAVE_FDOT2
                #pragma unroll
                for (int u = 0; u < 4; ++u) {
                    f16x2 pa = { av[2 * u], av[2 * u + 1] };
                    f16x2 pb = { bv[2 * u], bv[2 * u + 1] };
                    dot = __builtin_amdgcn_fdot2(pa, pb, dot, false);
                }
#else
                #pragma unroll
                for (int u = 0; u < 8; ++u)
                    dot = fmaf((float)av[u], (float)bv[u], dot);
#endif
            }
        }
        float d2 = fmaf(-2.f, dot, 2.f);
        float d  = sqrtf(fmaxf(d2, 1e-12f));           // reference clamp
        float tt = __builtin_amdgcn_exp2f(-d * K20);   // exp(-20 d)
        pS = __builtin_amdgcn_exp2f(d * K20);          // exp(+20 d)
        pL = tt * tt;
        float tp = (d2 * K2 < DTHR) ? 0.f : tt;        // what pair_kernel added
        subS = tp;
        subL = tp * tp;
    }

    // combine the 8 partner slots of this row
    #pragma unroll
    for (int m = 1; m < 8; m <<= 1) {
        pL   += __shfl_xor(pL, m, 64);
        pS   += __shfl_xor(pS, m, 64);
        subL += __shfl_xor(subL, m, 64);
        subS += __shfl_xor(subS, m, 64);
    }

    float v = 0.f;
    if (j == 0) {
        float nLv = sums[i] - subL;
        float nSv = sums[NROWS + i] - subS;
        float aLr  = 1.0f - pL / (pL + nLv);
        float posL = logf(pS) - 16.0f;    // log(sum exp(20(d-0.8)))
        float negL = logf(nSv) + 22.0f;   // log(sum exp(20(1.1-d)))
        v = aLr * (posL + negL);
    }
    #pragma unroll
    for (int m = 8; m < 64; m <<= 1) v += __shfl_xor(v, m, 64);

    __shared__ float partial[4];
    int wv = tid >> 6, lane = tid & 63;
    if (lane == 0) partial[wv] = v;
    __syncthreads();
    if (tid == 0) {
        float s = partial[0] + partial[1] + partial[2] + partial[3];
        atomicAdd(out, s * (1.0f / NROWS));
    }
}

extern "C" void kernel_launch(void* const* d_in, const int* in_sizes, int n_in,
                              void* d_out, int out_size, void* d_ws, size_t ws_size,
                              hipStream_t stream) {
    const float* x = (const float*)d_in[0];
    float* out = (float*)d_out;

    _Float16* xf = (_Float16*)d_ws;              // 2 MB, fragment-major
    float* sums  = (float*)(xf + NROWS * DDIM);  // 2*NROWS floats

    convert_kernel<<<NROWS * DDIM / (256 * 4), 256, 0, stream>>>(x, xf, sums, out);
    dim3 grid(NROWS / 128, NROWS / 256);         // 64 x 32 = 2048 blocks = 8192 waves
    pair_kernel<<<grid, 256, 0, stream>>>(xf, sums);
    finalize_kernel<<<NROWS / 32, 256, 0, stream>>>(xf, sums, out);
}

// Round 7
// 88.452 us; speedup vs baseline: 1.1920x; 1.1011x over previous
//
#include <hip/hip_runtime.h>
#include <math.h>

#define NROWS 8192
#define DDIM  128
#define K20   28.853900817779268f        // 20 * log2(e)
#define K2    (K20 * K20)                // 832.5476
#define DTHR  8.3255f                    // 0.01 * K2 (finalize subtraction mimic only)

typedef _Float16 f16x8 __attribute__((ext_vector_type(8)));
typedef _Float16 f16x4 __attribute__((ext_vector_type(4)));
typedef _Float16 f16x2 __attribute__((ext_vector_type(2)));
typedef float    f32x4 __attribute__((ext_vector_type(4)));

#ifndef __has_builtin
#define __has_builtin(x) 0
#endif
#if __has_builtin(__builtin_amdgcn_fdot2)
#define HAVE_FDOT2 1
#else
#define HAVE_FDOT2 0
#endif

// Fragment-major layout for mfma_f32_16x16x32_f16 (16-row groups):
//   xf[g*2048 + kk*512 + l*8 + j] = x[i = g*16 + (l&15)][k = kk*32 + (l>>4)*8 + j]
// -> a wave's A/B fragment load for one k-chunk is one contiguous 1 KB dwordx4.
// ws layout (floats after xf): sums[0..N) = nL (sum exp(-40d)), [N..2N) = nS (sum exp(-20d))

// ---- fp32 -> f16 frag-major transform + zero sums/out ----
__global__ void convert_kernel(const float* __restrict__ x,
                               _Float16* __restrict__ xf,
                               float* __restrict__ sums,
                               float* __restrict__ out) {
    int idx = (blockIdx.x * 256 + threadIdx.x) * 4;    // flat (i,k) element index
    float4 v = *(const float4*)(x + idx);
    f16x4 h = { (_Float16)v.x, (_Float16)v.y, (_Float16)v.z, (_Float16)v.w };
    const int i = idx >> 7, k = idx & 127;             // k multiple of 4
    const int lane = (((k >> 3) & 3) << 4) | (i & 15);
    const int dst = (i >> 4) * 2048 + (k >> 5) * 512 + lane * 8 + (k & 7);
    *(f16x4*)(xf + dst) = h;
    if (threadIdx.x < 16) sums[blockIdx.x * 16 + threadIdx.x] = 0.0f;  // 1024*16 = 2*NROWS
    if (blockIdx.x == 0 && threadIdx.x == 0) out[0] = 0.0f;
}

// ---- main pair kernel, symmetric: only strictly-upper elements (j > i) are
//      accumulated, each contributing to row i (direct, row-sum reduce +
//      atomic) AND row j (mirror, col-sum reduce via LDS + atomic). Blocks
//      entirely below the diagonal exit immediately (1056 of 2048 survive).
//      Wave = 32-row strip x 256-col segment (16 tiles of 16 cols), B tiles
//      register-double-buffered. Identical inner structure to the verified
//      round-6 kernel; the j>i compare replaces the DTHR self-mask. ----
__global__ __launch_bounds__(256, 4) void pair_kernel(
        const _Float16* __restrict__ xf,
        float* __restrict__ sums) {
    // keep block iff its 256-col segment reaches above the diagonal:
    // max col (256*by+255) >= min row (128*bx)  <=>  2*by+2 > bx
    if (2 * blockIdx.y + 2 <= blockIdx.x) return;

    __shared__ float shcL[4][256], shcS[4][256];

    const int w = threadIdx.x >> 6;
    const int lane = threadIdx.x & 63;
    const int ig = blockIdx.x * 4 + w;            // 32-row strip, 0..255
    const int i0 = ig * 32;
    const int ct0 = blockIdx.y * 16;              // first 16-col tile of segment

    // A fragments resident: 2 strips x 4 k-chunks, one 1 KB coalesced load each
    const _Float16* ab = xf + (size_t)(ig * 2) * 2048 + lane * 8;
    f16x8 a0[4], a1[4];
    #pragma unroll
    for (int kk = 0; kk < 4; ++kk) {
        a0[kk] = *(const f16x8*)(ab + kk * 512);
        a1[kk] = *(const f16x8*)(ab + 2048 + kk * 512);
    }

    float nL[8], nS[8];
    #pragma unroll
    for (int r = 0; r < 8; ++r) { nL[r] = 0.f; nS[r] = 0.f; }

    const _Float16* bb = xf + (size_t)ct0 * 2048 + lane * 8;

    f16x8 b0[4], b1[4];
    #pragma unroll
    for (int kk = 0; kk < 4; ++kk) b0[kk] = *(const f16x8*)(bb + kk * 512);

    auto compute = [&](f16x8 (&b)[4], int g) {
        f32x4 acc0 = {0.f,0.f,0.f,0.f}, acc1 = {0.f,0.f,0.f,0.f};
        #pragma unroll
        for (int kk = 0; kk < 4; ++kk) {
            acc0 = __builtin_amdgcn_mfma_f32_16x16x32_f16(a0[kk], b[kk], acc0, 0, 0, 0);
            acc1 = __builtin_amdgcn_mfma_f32_16x16x32_f16(a1[kk], b[kk], acc1, 0, 0, 0);
        }
        const int jcol = (ct0 + g) * 16 + (lane & 15);   // this lane's column
        float cs = 0.f, cl = 0.f;
        #pragma unroll
        for (int s = 0; s < 2; ++s) {
            const int ib = i0 + s * 16 + ((lane >> 4) << 2);  // C/D row base (m89/m91)
            #pragma unroll
            for (int r = 0; r < 4; ++r) {
                float acc = s ? acc1[r] : acc0[r];            // static indices
                float d2s = fmaf(-2.0f * K2, acc, 2.0f * K2); // (20*log2e)^2 * d^2
                float ds  = __builtin_amdgcn_sqrtf(d2s);      // NaN on self, masked below
                float tt  = __builtin_amdgcn_exp2f(-ds);      // exp(-20 d)
                tt = (jcol > ib + r) ? tt : 0.0f;             // strictly-upper only
                nS[s * 4 + r] += tt;
                nL[s * 4 + r] = fmaf(tt, tt, nL[s * 4 + r]);  // exp(-40 d)
                cs += tt;
                cl = fmaf(tt, tt, cl);
            }
        }
        // mirror: reduce over the wave's 32 rows (row groups at lane bits 4,5)
        cs += __shfl_xor(cs, 16, 64);  cl += __shfl_xor(cl, 16, 64);
        cs += __shfl_xor(cs, 32, 64);  cl += __shfl_xor(cl, 32, 64);
        if (lane < 16) { shcS[w][g * 16 + lane] = cs; shcL[w][g * 16 + lane] = cl; }
    };

    // 16 col-tiles, 1-ahead register double buffer (wrap reload on last: harmless)
    for (int g = 0; g < 16; g += 2) {
        const _Float16* p1 = bb + (size_t)(g + 1) * 2048;
        #pragma unroll
        for (int kk = 0; kk < 4; ++kk) b1[kk] = *(const f16x8*)(p1 + kk * 512);
        compute(b0, g);
        const _Float16* p2 = bb + (size_t)((g + 2) & 15) * 2048;
        #pragma unroll
        for (int kk = 0; kk < 4; ++kk) b0[kk] = *(const f16x8*)(p2 + kk * 512);
        compute(b1, g + 1);
    }

    // direct row sums: reduce across the 16 column-lanes, atomic into sums[row]
    #pragma unroll
    for (int s = 0; s < 2; ++s) {
        #pragma unroll
        for (int r = 0; r < 4; ++r) {
            float aa = nL[s * 4 + r], ss = nS[s * 4 + r];
            #pragma unroll
            for (int m = 1; m < 16; m <<= 1) {
                aa += __shfl_xor(aa, m, 64);
                ss += __shfl_xor(ss, m, 64);
            }
            if ((lane & 15) == 0) {
                const int row = i0 + s * 16 + (lane >> 4) * 4 + r;
                atomicAdd(&sums[row], aa);
                atomicAdd(&sums[NROWS + row], ss);
            }
        }
    }

    // mirrored col sums: combine the 4 waves, one atomic per column
    __syncthreads();
    {
        const int c = threadIdx.x;                 // 256 threads = 256 segment cols
        const int col = ct0 * 16 + c;
        float mL = shcL[0][c] + shcL[1][c] + shcL[2][c] + shcL[3][c];
        float mS = shcS[0][c] + shcS[1][c] + shcS[2][c] + shcS[3][c];
        atomicAdd(&sums[col], mL);
        atomicAdd(&sums[NROWS + col], mS);
    }
}

// ---- finalize + positive-pair correction, 8 threads per row (1024 waves).
//      Thread j of row i computes the single partner jj=j (skipped when j==ii),
//      then a 3-step shuffle combine; lane j==0 finishes the per-row loss. ----
__global__ void finalize_kernel(const _Float16* __restrict__ xf,
                                const float* __restrict__ sums,
                                float* __restrict__ out) {
    const int tid = threadIdx.x;
    const int i = blockIdx.x * 32 + (tid >> 3);   // row
    const int j = tid & 7;                        // partner slot
    const int g = i >> 4, ri = i & 15, ii = i & 7;
    const _Float16* base = xf + (size_t)g * 2048;

    float pL = 0.f, pS = 0.f, subL = 0.f, subS = 0.f;
    if (j != ii) {
        const int rj = ri - ii + j;               // same 16-row group (classes 8-aligned)
        float dot = 0.f;
        #pragma unroll
        for (int kk = 0; kk < 4; ++kk) {
            #pragma unroll
            for (int h = 0; h < 4; ++h) {
                f16x8 av = *(const f16x8*)(base + kk * 512 + ((h << 4) | ri) * 8);
                f16x8 bv = *(const f16x8*)(base + kk * 512 + ((h << 4) | rj) * 8);
#if HAVE_FDOT2
                #pragma unroll
                for (int u = 0; u < 4; ++u) {
                    f16x2 pa = { av[2 * u], av[2 * u + 1] };
                    f16x2 pb = { bv[2 * u], bv[2 * u + 1] };
                    dot = __builtin_amdgcn_fdot2(pa, pb, dot, false);
                }
#else
                #pragma unroll
                for (int u = 0; u < 8; ++u)
                    dot = fmaf((float)av[u], (float)bv[u], dot);
#endif
            }
        }
        float d2 = fmaf(-2.f, dot, 2.f);
        float d  = sqrtf(fmaxf(d2, 1e-12f));           // reference clamp
        float tt = __builtin_amdgcn_exp2f(-d * K20);   // exp(-20 d)
        pS = __builtin_amdgcn_exp2f(d * K20);          // exp(+20 d)
        pL = tt * tt;
        float tp = (d2 * K2 < DTHR) ? 0.f : tt;        // what pair_kernel added
        subS = tp;
        subL = tp * tp;
    }

    // combine the 8 partner slots of this row
    #pragma unroll
    for (int m = 1; m < 8; m <<= 1) {
        pL   += __shfl_xor(pL, m, 64);
        pS   += __shfl_xor(pS, m, 64);
        subL += __shfl_xor(subL, m, 64);
        subS += __shfl_xor(subS, m, 64);
    }

    float v = 0.f;
    if (j == 0) {
        float nLv = sums[i] - subL;
        float nSv = sums[NROWS + i] - subS;
        float aLr  = 1.0f - pL / (pL + nLv);
        float posL = logf(pS) - 16.0f;    // log(sum exp(20(d-0.8)))
        float negL = logf(nSv) + 22.0f;   // log(sum exp(20(1.1-d)))
        v = aLr * (posL + negL);
    }
    #pragma unroll
    for (int m = 8; m < 64; m <<= 1) v += __shfl_xor(v, m, 64);

    __shared__ float partial[4];
    int wv = tid >> 6, lane = tid & 63;
    if (lane == 0) partial[wv] = v;
    __syncthreads();
    if (tid == 0) {
        float s = partial[0] + partial[1] + partial[2] + partial[3];
        atomicAdd(out, s * (1.0f / NROWS));
    }
}

extern "C" void kernel_launch(void* const* d_in, const int* in_sizes, int n_in,
                              void* d_out, int out_size, void* d_ws, size_t ws_size,
                              hipStream_t stream) {
    const float* x = (const float*)d_in[0];
    float* out = (float*)d_out;

    _Float16* xf = (_Float16*)d_ws;              // 2 MB, fragment-major
    float* sums  = (float*)(xf + NROWS * DDIM);  // 2*NROWS floats

    convert_kernel<<<NROWS * DDIM / (256 * 4), 256, 0, stream>>>(x, xf, sums, out);
    dim3 grid(NROWS / 128, NROWS / 256);         // 64 x 32; lower-triangle blocks exit
    pair_kernel<<<grid, 256, 0, stream>>>(xf, sums);
    finalize_kernel<<<NROWS / 32, 256, 0, stream>>>(xf, sums, out);
}